// Round 2
// baseline (301.127 us; speedup 1.0000x reference)
//
#include <hip/hip_runtime.h>
#include <math.h>

#define EPS_Q 1e-8f

struct F3 { float x, y, z; };
struct Q4 { F3 v; float w; };

__device__ __forceinline__ F3 add3(F3 a, F3 b){ return {a.x+b.x, a.y+b.y, a.z+b.z}; }
__device__ __forceinline__ F3 sub3(F3 a, F3 b){ return {a.x-b.x, a.y-b.y, a.z-b.z}; }
__device__ __forceinline__ F3 scal3(float s, F3 a){ return {s*a.x, s*a.y, s*a.z}; }
__device__ __forceinline__ float dot3(F3 a, F3 b){ return a.x*b.x + a.y*b.y + a.z*b.z; }
__device__ __forceinline__ F3 cross3(F3 a, F3 b){
    return { a.y*b.z - a.z*b.y, a.z*b.x - a.x*b.z, a.x*b.y - a.y*b.x };
}
__device__ __forceinline__ Q4 qmul(Q4 q, Q4 r){
    Q4 o;
    o.w = q.w*r.w - dot3(q.v, r.v);
    o.v = add3(add3(scal3(q.w, r.v), scal3(r.w, q.v)), cross3(q.v, r.v));
    return o;
}
__device__ __forceinline__ Q4 qconj(Q4 q){ return { {-q.v.x, -q.v.y, -q.v.z}, q.w }; }
__device__ __forceinline__ F3 qrot(Q4 q, F3 v){
    F3 t = scal3(2.0f, cross3(q.v, v));
    return add3(add3(v, scal3(q.w, t)), cross3(q.v, t));
}
__device__ __forceinline__ F3 so3_log(Q4 q){
    float n = sqrtf(dot3(q.v, q.v));
    float theta = 2.0f * atan2f(n, q.w);
    float k;
    if (n > EPS_Q) k = theta / n;
    else           k = 2.0f / ((fabsf(q.w) > EPS_Q) ? q.w : 1.0f);
    return scal3(k, q.v);
}

// full edge residual given unpacked operands; writes 6 floats nontemporally
__device__ __forceinline__ void edge_compute(F3 t1, Q4 q1, F3 t2, Q4 q2,
                                             F3 tp, Q4 qp, float* __restrict__ o)
{
    Q4 qi1 = qconj(q1);
    F3 ti1 = scal3(-1.0f, qrot(qi1, t1));
    Q4 qa  = qmul(qi1, q2);
    F3 ta  = add3(ti1, qrot(qi1, t2));

    Q4 qip = qconj(qp);
    F3 tip = scal3(-1.0f, qrot(qip, tp));
    Q4 qe  = qmul(qip, qa);
    F3 te  = add3(tip, qrot(qip, ta));

    F3 phi = so3_log(qe);
    float theta2 = dot3(phi, phi);
    float theta  = sqrtf(theta2);
    float coef;
    if (theta < 1e-4f) {
        coef = 1.0f / 12.0f;
    } else {
        coef = 1.0f / theta2 - (1.0f + cosf(theta)) / (2.0f * theta * sinf(theta));
    }
    F3 pxt = cross3(phi, te);
    F3 tau = add3(sub3(te, scal3(0.5f, pxt)), scal3(coef, cross3(phi, pxt)));

    __builtin_nontemporal_store(tau.x, o + 0);
    __builtin_nontemporal_store(tau.y, o + 1);
    __builtin_nontemporal_store(tau.z, o + 2);
    __builtin_nontemporal_store(phi.x, o + 3);
    __builtin_nontemporal_store(phi.y, o + 4);
    __builtin_nontemporal_store(phi.z, o + 5);
}

// ---------------- pad nodes: 7 floats -> 2x float4 (32 B aligned) ----------------
__global__ void pad_nodes_kernel(const float* __restrict__ nodes,
                                 float4* __restrict__ pn, int N)
{
    int i = blockIdx.x * blockDim.x + threadIdx.x;
    if (i >= N) return;
    const float* s = nodes + 7*(size_t)i;
    float4 a = { s[0], s[1], s[2], s[3] };
    float4 b = { s[4], s[5], s[6], 0.0f };
    pn[2*(size_t)i    ] = a;
    pn[2*(size_t)i + 1] = b;
}

// ---------------- fused main: edges (2/thread) + node residuals ----------------
__global__ void fused_main(const int*    __restrict__ edges,
                           const float4* __restrict__ pn,
                           const float*  __restrict__ poses,
                           const float*  __restrict__ vels,
                           const float*  __restrict__ imu_drots,
                           const float*  __restrict__ imu_dtrans,
                           const float*  __restrict__ imu_dvels,
                           const float*  __restrict__ dts,
                           float*        __restrict__ out,
                           int E, int M, int edge_threads)
{
    int tid = blockIdx.x * blockDim.x + threadIdx.x;
    if (tid < edge_threads) {
        int e0 = 2*tid;
        int e1 = e0 + 1;
        bool has1 = (e1 < E);
        int e1s = has1 ? e1 : e0;

        // edge indices (single-use -> nontemporal)
        int i0 = __builtin_nontemporal_load(edges + 2*(size_t)e0);
        int j0 = __builtin_nontemporal_load(edges + 2*(size_t)e0 + 1);
        int i1 = __builtin_nontemporal_load(edges + 2*(size_t)e1s);
        int j1 = __builtin_nontemporal_load(edges + 2*(size_t)e1s + 1);

        // padded-node gathers: 2x dwordx4 each, cacheable (reuse across edges)
        float4 na0 = pn[2*(size_t)i0], na1 = pn[2*(size_t)i0 + 1];
        float4 nb0 = pn[2*(size_t)j0], nb1 = pn[2*(size_t)j0 + 1];
        float4 nc0 = pn[2*(size_t)i1], nc1 = pn[2*(size_t)i1 + 1];
        float4 nd0 = pn[2*(size_t)j1], nd1 = pn[2*(size_t)j1 + 1];

        // pose streams (single-use -> nontemporal)
        const float* p0 = poses + 7*(size_t)e0;
        const float* p1 = poses + 7*(size_t)e1s;
        float pp0[7], pp1[7];
        #pragma unroll
        for (int k = 0; k < 7; ++k) pp0[k] = __builtin_nontemporal_load(p0 + k);
        #pragma unroll
        for (int k = 0; k < 7; ++k) pp1[k] = __builtin_nontemporal_load(p1 + k);

        {
            F3 t1 = {na0.x, na0.y, na0.z};  Q4 q1 = {{na0.w, na1.x, na1.y}, na1.z};
            F3 t2 = {nb0.x, nb0.y, nb0.z};  Q4 q2 = {{nb0.w, nb1.x, nb1.y}, nb1.z};
            F3 tp = {pp0[0], pp0[1], pp0[2]}; Q4 qp = {{pp0[3], pp0[4], pp0[5]}, pp0[6]};
            edge_compute(t1, q1, t2, q2, tp, qp, out + 6*(size_t)e0);
        }
        if (has1) {
            F3 t1 = {nc0.x, nc0.y, nc0.z};  Q4 q1 = {{nc0.w, nc1.x, nc1.y}, nc1.z};
            F3 t2 = {nd0.x, nd0.y, nd0.z};  Q4 q2 = {{nd0.w, nd1.x, nd1.y}, nd1.z};
            F3 tp = {pp1[0], pp1[1], pp1[2]}; Q4 qp = {{pp1[3], pp1[4], pp1[5]}, pp1[6]};
            edge_compute(t1, q1, t2, q2, tp, qp, out + 6*(size_t)e1);
        }
    } else {
        int m = tid - edge_threads;
        if (m >= M) return;

        const size_t off_adjvel   = 6*(size_t)E;
        const size_t off_imurot   = off_adjvel + 3*(size_t)M;
        const size_t off_transvel = off_imurot + 3*(size_t)M;

        // sequential padded-node reads (adjacent threads share lines -> cacheable)
        float4 n0a = pn[2*(size_t)m    ], n0b = pn[2*(size_t)m + 1];
        float4 n1a = pn[2*(size_t)m + 2], n1b = pn[2*(size_t)m + 3];
        F3 t0 = {n0a.x, n0a.y, n0a.z};  Q4 q0 = {{n0a.w, n0b.x, n0b.y}, n0b.z};
        F3 t1 = {n1a.x, n1a.y, n1a.z};  Q4 q1 = {{n1a.w, n1b.x, n1b.y}, n1b.z};

        F3 v0 = {vels[3*(size_t)m],     vels[3*(size_t)m + 1], vels[3*(size_t)m + 2]};
        F3 v1 = {vels[3*(size_t)m + 3], vels[3*(size_t)m + 4], vels[3*(size_t)m + 5]};

        // adjvelerr (L2 = 0.1)
        F3 dvm = { __builtin_nontemporal_load(imu_dvels + 3*(size_t)m),
                   __builtin_nontemporal_load(imu_dvels + 3*(size_t)m + 1),
                   __builtin_nontemporal_load(imu_dvels + 3*(size_t)m + 2) };
        F3 adjv = sub3(dvm, sub3(v1, v0));
        __builtin_nontemporal_store(0.1f * adjv.x, out + off_adjvel + 3*(size_t)m);
        __builtin_nontemporal_store(0.1f * adjv.y, out + off_adjvel + 3*(size_t)m + 1);
        __builtin_nontemporal_store(0.1f * adjv.z, out + off_adjvel + 3*(size_t)m + 2);

        // imuroterr (L3 = 1.0): imu_drots is 16-B aligned -> float4
        const float4 drv = ((const float4*)imu_drots)[m];
        Q4 dr = {{drv.x, drv.y, drv.z}, drv.w};
        Q4 qre = qmul(qconj(dr), qmul(qconj(q0), q1));
        F3 rot = so3_log(qre);
        __builtin_nontemporal_store(rot.x, out + off_imurot + 3*(size_t)m);
        __builtin_nontemporal_store(rot.y, out + off_imurot + 3*(size_t)m + 1);
        __builtin_nontemporal_store(rot.z, out + off_imurot + 3*(size_t)m + 2);

        // transvelerr (L4 = 0.1)
        float dt = dts[m];
        F3 dtr = { __builtin_nontemporal_load(imu_dtrans + 3*(size_t)m),
                   __builtin_nontemporal_load(imu_dtrans + 3*(size_t)m + 1),
                   __builtin_nontemporal_load(imu_dtrans + 3*(size_t)m + 2) };
        F3 tv = sub3(sub3(t1, t0), add3(scal3(dt, v0), dtr));
        __builtin_nontemporal_store(0.1f * tv.x, out + off_transvel + 3*(size_t)m);
        __builtin_nontemporal_store(0.1f * tv.y, out + off_transvel + 3*(size_t)m + 1);
        __builtin_nontemporal_store(0.1f * tv.z, out + off_transvel + 3*(size_t)m + 2);
    }
}

// ---------------- fallback path (if ws too small): round-1 kernels ----------------
__global__ void edge_kernel(const int*   __restrict__ edges,
                            const float* __restrict__ nodes,
                            const float* __restrict__ poses,
                            float*       __restrict__ out,
                            int E)
{
    int e = blockIdx.x * blockDim.x + threadIdx.x;
    if (e >= E) return;
    int i = edges[2*(size_t)e];
    int j = edges[2*(size_t)e + 1];
    const float* n1 = nodes + 7*(size_t)i;
    const float* n2 = nodes + 7*(size_t)j;
    const float* p  = poses + 7*(size_t)e;
    F3 t1 = {n1[0], n1[1], n1[2]};  Q4 q1 = {{n1[3], n1[4], n1[5]}, n1[6]};
    F3 t2 = {n2[0], n2[1], n2[2]};  Q4 q2 = {{n2[3], n2[4], n2[5]}, n2[6]};
    F3 tp = {p[0],  p[1],  p[2]};   Q4 qp = {{p[3],  p[4],  p[5]},  p[6]};
    edge_compute(t1, q1, t2, q2, tp, qp, out + 6*(size_t)e);
}

__global__ void node_kernel(const float* __restrict__ nodes,
                            const float* __restrict__ vels,
                            const float* __restrict__ imu_drots,
                            const float* __restrict__ imu_dtrans,
                            const float* __restrict__ imu_dvels,
                            const float* __restrict__ dts,
                            float*       __restrict__ out,
                            int M,
                            size_t off_adjvel, size_t off_imurot, size_t off_transvel)
{
    int m = blockIdx.x * blockDim.x + threadIdx.x;
    if (m >= M) return;
    const float* n0 = nodes + 7*(size_t)m;
    const float* n1 = nodes + 7*(size_t)(m+1);
    F3 t0 = {n0[0], n0[1], n0[2]};  Q4 q0 = {{n0[3], n0[4], n0[5]}, n0[6]};
    F3 t1 = {n1[0], n1[1], n1[2]};  Q4 q1 = {{n1[3], n1[4], n1[5]}, n1[6]};
    F3 v0 = {vels[3*(size_t)m],     vels[3*(size_t)m + 1], vels[3*(size_t)m + 2]};
    F3 v1 = {vels[3*(size_t)m + 3], vels[3*(size_t)m + 4], vels[3*(size_t)m + 5]};
    F3 dvm = {imu_dvels[3*(size_t)m], imu_dvels[3*(size_t)m + 1], imu_dvels[3*(size_t)m + 2]};
    F3 adjv = sub3(dvm, sub3(v1, v0));
    out[off_adjvel + 3*(size_t)m    ] = 0.1f * adjv.x;
    out[off_adjvel + 3*(size_t)m + 1] = 0.1f * adjv.y;
    out[off_adjvel + 3*(size_t)m + 2] = 0.1f * adjv.z;
    Q4 dr = {{imu_drots[4*(size_t)m], imu_drots[4*(size_t)m + 1], imu_drots[4*(size_t)m + 2]},
              imu_drots[4*(size_t)m + 3]};
    Q4 qre = qmul(qconj(dr), qmul(qconj(q0), q1));
    F3 rot = so3_log(qre);
    out[off_imurot + 3*(size_t)m    ] = rot.x;
    out[off_imurot + 3*(size_t)m + 1] = rot.y;
    out[off_imurot + 3*(size_t)m + 2] = rot.z;
    float dt = dts[m];
    F3 dtr = {imu_dtrans[3*(size_t)m], imu_dtrans[3*(size_t)m + 1], imu_dtrans[3*(size_t)m + 2]};
    F3 tv = sub3(sub3(t1, t0), add3(scal3(dt, v0), dtr));
    out[off_transvel + 3*(size_t)m    ] = 0.1f * tv.x;
    out[off_transvel + 3*(size_t)m + 1] = 0.1f * tv.y;
    out[off_transvel + 3*(size_t)m + 2] = 0.1f * tv.z;
}

extern "C" void kernel_launch(void* const* d_in, const int* in_sizes, int n_in,
                              void* d_out, int out_size, void* d_ws, size_t ws_size,
                              hipStream_t stream) {
    const int*   edges      = (const int*)  d_in[0];
    const float* nodes      = (const float*)d_in[1];
    const float* vels       = (const float*)d_in[2];
    const float* poses      = (const float*)d_in[3];
    const float* imu_drots  = (const float*)d_in[4];
    const float* imu_dtrans = (const float*)d_in[5];
    const float* imu_dvels  = (const float*)d_in[6];
    const float* dts        = (const float*)d_in[7];
    float* out = (float*)d_out;

    const int E = in_sizes[0] / 2;
    const int N = in_sizes[1] / 7;
    const int M = in_sizes[7];

    const int BLK = 256;
    const size_t need = 2 * (size_t)N * sizeof(float4);   // 32 B per node

    if (ws_size >= need) {
        float4* pn = (float4*)d_ws;
        pad_nodes_kernel<<<(N + BLK - 1) / BLK, BLK, 0, stream>>>(nodes, pn, N);
        const int edge_threads = (E + 1) / 2;
        const long long total = (long long)edge_threads + M;
        fused_main<<<(int)((total + BLK - 1) / BLK), BLK, 0, stream>>>(
            edges, pn, poses, vels, imu_drots, imu_dtrans, imu_dvels, dts,
            out, E, M, edge_threads);
    } else {
        const size_t off_adjvel   = 6*(size_t)E;
        const size_t off_imurot   = off_adjvel + 3*(size_t)M;
        const size_t off_transvel = off_imurot + 3*(size_t)M;
        edge_kernel<<<(E + BLK - 1) / BLK, BLK, 0, stream>>>(edges, nodes, poses, out, E);
        node_kernel<<<(M + BLK - 1) / BLK, BLK, 0, stream>>>(nodes, vels, imu_drots, imu_dtrans,
                                                             imu_dvels, dts, out, M,
                                                             off_adjvel, off_imurot, off_transvel);
    }
}

// Round 3
// 275.758 us; speedup vs baseline: 1.0920x; 1.0920x over previous
//
#include <hip/hip_runtime.h>
#include <math.h>

#define EPS_Q 1e-8f

struct F3 { float x, y, z; };
struct Q4 { F3 v; float w; };

__device__ __forceinline__ F3 add3(F3 a, F3 b){ return {a.x+b.x, a.y+b.y, a.z+b.z}; }
__device__ __forceinline__ F3 sub3(F3 a, F3 b){ return {a.x-b.x, a.y-b.y, a.z-b.z}; }
__device__ __forceinline__ F3 scal3(float s, F3 a){ return {s*a.x, s*a.y, s*a.z}; }
__device__ __forceinline__ float dot3(F3 a, F3 b){ return a.x*b.x + a.y*b.y + a.z*b.z; }
__device__ __forceinline__ F3 cross3(F3 a, F3 b){
    return { a.y*b.z - a.z*b.y, a.z*b.x - a.x*b.z, a.x*b.y - a.y*b.x };
}
__device__ __forceinline__ Q4 qmul(Q4 q, Q4 r){
    Q4 o;
    o.w = q.w*r.w - dot3(q.v, r.v);
    o.v = add3(add3(scal3(q.w, r.v), scal3(r.w, q.v)), cross3(q.v, r.v));
    return o;
}
__device__ __forceinline__ Q4 qconj(Q4 q){ return { {-q.v.x, -q.v.y, -q.v.z}, q.w }; }
__device__ __forceinline__ F3 qrot(Q4 q, F3 v){
    F3 t = scal3(2.0f, cross3(q.v, v));
    return add3(add3(v, scal3(q.w, t)), cross3(q.v, t));
}
__device__ __forceinline__ F3 so3_log(Q4 q){
    float n = sqrtf(dot3(q.v, q.v));
    float theta = 2.0f * atan2f(n, q.w);
    float k;
    if (n > EPS_Q) k = theta / n;
    else           k = 2.0f / ((fabsf(q.w) > EPS_Q) ? q.w : 1.0f);
    return scal3(k, q.v);
}

// full edge residual given unpacked operands; plain stores (L1 = 1.0)
__device__ __forceinline__ void edge_compute(F3 t1, Q4 q1, F3 t2, Q4 q2,
                                             F3 tp, Q4 qp, float* __restrict__ o)
{
    Q4 qi1 = qconj(q1);
    F3 ti1 = scal3(-1.0f, qrot(qi1, t1));
    Q4 qa  = qmul(qi1, q2);
    F3 ta  = add3(ti1, qrot(qi1, t2));

    Q4 qip = qconj(qp);
    F3 tip = scal3(-1.0f, qrot(qip, tp));
    Q4 qe  = qmul(qip, qa);
    F3 te  = add3(tip, qrot(qip, ta));

    F3 phi = so3_log(qe);
    float theta2 = dot3(phi, phi);
    float theta  = sqrtf(theta2);
    float coef;
    if (theta < 1e-4f) {
        coef = 1.0f / 12.0f;
    } else {
        coef = 1.0f / theta2 - (1.0f + cosf(theta)) / (2.0f * theta * sinf(theta));
    }
    F3 pxt = cross3(phi, te);
    F3 tau = add3(sub3(te, scal3(0.5f, pxt)), scal3(coef, cross3(phi, pxt)));

    o[0] = tau.x; o[1] = tau.y; o[2] = tau.z;
    o[3] = phi.x; o[4] = phi.y; o[5] = phi.z;
}

// ---------------- pad nodes: 7 floats -> 2x float4 (32 B per node) ----------------
__global__ void pad_nodes_kernel(const float* __restrict__ nodes,
                                 float4* __restrict__ pn, int N)
{
    int i = blockIdx.x * blockDim.x + threadIdx.x;
    if (i >= N) return;
    const float* s = nodes + 7*(size_t)i;
    float4 a = { s[0], s[1], s[2], s[3] };
    float4 b = { s[4], s[5], s[6], 0.0f };
    pn[2*(size_t)i    ] = a;
    pn[2*(size_t)i + 1] = b;
}

// ---------------- edge kernel: 2 edges/thread (split halves), plain stores ----------------
__global__ void edge_kernel2(const int2*   __restrict__ edges,
                             const float4* __restrict__ pn,
                             const float*  __restrict__ poses,
                             float*        __restrict__ out,
                             int E, int half)
{
    int t = blockIdx.x * blockDim.x + threadIdx.x;
    if (t >= half) return;
    int e0 = t;
    int e1 = t + half;
    bool has1 = (e1 < E);
    int e1s = has1 ? e1 : e0;

    // edge indices: one dwordx2 each
    int2 ab0 = edges[e0];
    int2 ab1 = edges[e1s];

    // padded-node gathers: 2x dwordx4 each -> 8 independent 16-B loads in flight
    float4 na0 = pn[2*(size_t)ab0.x], na1 = pn[2*(size_t)ab0.x + 1];
    float4 nb0 = pn[2*(size_t)ab0.y], nb1 = pn[2*(size_t)ab0.y + 1];
    float4 nc0 = pn[2*(size_t)ab1.x], nc1 = pn[2*(size_t)ab1.x + 1];
    float4 nd0 = pn[2*(size_t)ab1.y], nd1 = pn[2*(size_t)ab1.y + 1];

    // pose streams: plain scalar loads (L1 absorbs the 7-dword overlap)
    const float* p0 = poses + 7*(size_t)e0;
    const float* p1 = poses + 7*(size_t)e1s;
    float pp0[7], pp1[7];
    #pragma unroll
    for (int k = 0; k < 7; ++k) pp0[k] = p0[k];
    #pragma unroll
    for (int k = 0; k < 7; ++k) pp1[k] = p1[k];

    {
        F3 t1 = {na0.x, na0.y, na0.z};  Q4 q1 = {{na0.w, na1.x, na1.y}, na1.z};
        F3 t2 = {nb0.x, nb0.y, nb0.z};  Q4 q2 = {{nb0.w, nb1.x, nb1.y}, nb1.z};
        F3 tp = {pp0[0], pp0[1], pp0[2]}; Q4 qp = {{pp0[3], pp0[4], pp0[5]}, pp0[6]};
        edge_compute(t1, q1, t2, q2, tp, qp, out + 6*(size_t)e0);
    }
    if (has1) {
        F3 t1 = {nc0.x, nc0.y, nc0.z};  Q4 q1 = {{nc0.w, nc1.x, nc1.y}, nc1.z};
        F3 t2 = {nd0.x, nd0.y, nd0.z};  Q4 q2 = {{nd0.w, nd1.x, nd1.y}, nd1.z};
        F3 tp = {pp1[0], pp1[1], pp1[2]}; Q4 qp = {{pp1[3], pp1[4], pp1[5]}, pp1[6]};
        edge_compute(t1, q1, t2, q2, tp, qp, out + 6*(size_t)e1);
    }
}

// ---------------- node residuals: plain loads/stores, vectorized where aligned ----------------
__global__ void node_kernel(const float4* __restrict__ pn,
                            const float*  __restrict__ vels,
                            const float4* __restrict__ imu_drots,
                            const float*  __restrict__ imu_dtrans,
                            const float*  __restrict__ imu_dvels,
                            const float*  __restrict__ dts,
                            float*        __restrict__ out,
                            int M,
                            size_t off_adjvel, size_t off_imurot, size_t off_transvel)
{
    int m = blockIdx.x * blockDim.x + threadIdx.x;
    if (m >= M) return;

    float4 n0a = pn[2*(size_t)m    ], n0b = pn[2*(size_t)m + 1];
    float4 n1a = pn[2*(size_t)m + 2], n1b = pn[2*(size_t)m + 3];
    F3 t0 = {n0a.x, n0a.y, n0a.z};  Q4 q0 = {{n0a.w, n0b.x, n0b.y}, n0b.z};
    F3 t1 = {n1a.x, n1a.y, n1a.z};  Q4 q1 = {{n1a.w, n1b.x, n1b.y}, n1b.z};

    F3 v0 = {vels[3*(size_t)m],     vels[3*(size_t)m + 1], vels[3*(size_t)m + 2]};
    F3 v1 = {vels[3*(size_t)m + 3], vels[3*(size_t)m + 4], vels[3*(size_t)m + 5]};

    // adjvelerr (L2 = 0.1)
    F3 dvm = {imu_dvels[3*(size_t)m], imu_dvels[3*(size_t)m + 1], imu_dvels[3*(size_t)m + 2]};
    F3 adjv = sub3(dvm, sub3(v1, v0));
    out[off_adjvel + 3*(size_t)m    ] = 0.1f * adjv.x;
    out[off_adjvel + 3*(size_t)m + 1] = 0.1f * adjv.y;
    out[off_adjvel + 3*(size_t)m + 2] = 0.1f * adjv.z;

    // imuroterr (L3 = 1.0)
    float4 drv = imu_drots[m];
    Q4 dr = {{drv.x, drv.y, drv.z}, drv.w};
    Q4 qre = qmul(qconj(dr), qmul(qconj(q0), q1));
    F3 rot = so3_log(qre);
    out[off_imurot + 3*(size_t)m    ] = rot.x;
    out[off_imurot + 3*(size_t)m + 1] = rot.y;
    out[off_imurot + 3*(size_t)m + 2] = rot.z;

    // transvelerr (L4 = 0.1)
    float dt = dts[m];
    F3 dtr = {imu_dtrans[3*(size_t)m], imu_dtrans[3*(size_t)m + 1], imu_dtrans[3*(size_t)m + 2]};
    F3 tv = sub3(sub3(t1, t0), add3(scal3(dt, v0), dtr));
    out[off_transvel + 3*(size_t)m    ] = 0.1f * tv.x;
    out[off_transvel + 3*(size_t)m + 1] = 0.1f * tv.y;
    out[off_transvel + 3*(size_t)m + 2] = 0.1f * tv.z;
}

// ---------------- fallback (ws too small): unpadded versions ----------------
__global__ void edge_kernel(const int*   __restrict__ edges,
                            const float* __restrict__ nodes,
                            const float* __restrict__ poses,
                            float*       __restrict__ out,
                            int E)
{
    int e = blockIdx.x * blockDim.x + threadIdx.x;
    if (e >= E) return;
    int i = edges[2*(size_t)e];
    int j = edges[2*(size_t)e + 1];
    const float* n1 = nodes + 7*(size_t)i;
    const float* n2 = nodes + 7*(size_t)j;
    const float* p  = poses + 7*(size_t)e;
    F3 t1 = {n1[0], n1[1], n1[2]};  Q4 q1 = {{n1[3], n1[4], n1[5]}, n1[6]};
    F3 t2 = {n2[0], n2[1], n2[2]};  Q4 q2 = {{n2[3], n2[4], n2[5]}, n2[6]};
    F3 tp = {p[0],  p[1],  p[2]};   Q4 qp = {{p[3],  p[4],  p[5]},  p[6]};
    edge_compute(t1, q1, t2, q2, tp, qp, out + 6*(size_t)e);
}

__global__ void node_kernel_raw(const float* __restrict__ nodes,
                                const float* __restrict__ vels,
                                const float* __restrict__ imu_drots,
                                const float* __restrict__ imu_dtrans,
                                const float* __restrict__ imu_dvels,
                                const float* __restrict__ dts,
                                float*       __restrict__ out,
                                int M,
                                size_t off_adjvel, size_t off_imurot, size_t off_transvel)
{
    int m = blockIdx.x * blockDim.x + threadIdx.x;
    if (m >= M) return;
    const float* n0 = nodes + 7*(size_t)m;
    const float* n1 = nodes + 7*(size_t)(m+1);
    F3 t0 = {n0[0], n0[1], n0[2]};  Q4 q0 = {{n0[3], n0[4], n0[5]}, n0[6]};
    F3 t1 = {n1[0], n1[1], n1[2]};  Q4 q1 = {{n1[3], n1[4], n1[5]}, n1[6]};
    F3 v0 = {vels[3*(size_t)m],     vels[3*(size_t)m + 1], vels[3*(size_t)m + 2]};
    F3 v1 = {vels[3*(size_t)m + 3], vels[3*(size_t)m + 4], vels[3*(size_t)m + 5]};
    F3 dvm = {imu_dvels[3*(size_t)m], imu_dvels[3*(size_t)m + 1], imu_dvels[3*(size_t)m + 2]};
    F3 adjv = sub3(dvm, sub3(v1, v0));
    out[off_adjvel + 3*(size_t)m    ] = 0.1f * adjv.x;
    out[off_adjvel + 3*(size_t)m + 1] = 0.1f * adjv.y;
    out[off_adjvel + 3*(size_t)m + 2] = 0.1f * adjv.z;
    Q4 dr = {{imu_drots[4*(size_t)m], imu_drots[4*(size_t)m + 1], imu_drots[4*(size_t)m + 2]},
              imu_drots[4*(size_t)m + 3]};
    Q4 qre = qmul(qconj(dr), qmul(qconj(q0), q1));
    F3 rot = so3_log(qre);
    out[off_imurot + 3*(size_t)m    ] = rot.x;
    out[off_imurot + 3*(size_t)m + 1] = rot.y;
    out[off_imurot + 3*(size_t)m + 2] = rot.z;
    float dt = dts[m];
    F3 dtr = {imu_dtrans[3*(size_t)m], imu_dtrans[3*(size_t)m + 1], imu_dtrans[3*(size_t)m + 2]};
    F3 tv = sub3(sub3(t1, t0), add3(scal3(dt, v0), dtr));
    out[off_transvel + 3*(size_t)m    ] = 0.1f * tv.x;
    out[off_transvel + 3*(size_t)m + 1] = 0.1f * tv.y;
    out[off_transvel + 3*(size_t)m + 2] = 0.1f * tv.z;
}

extern "C" void kernel_launch(void* const* d_in, const int* in_sizes, int n_in,
                              void* d_out, int out_size, void* d_ws, size_t ws_size,
                              hipStream_t stream) {
    const int*   edges      = (const int*)  d_in[0];
    const float* nodes      = (const float*)d_in[1];
    const float* vels       = (const float*)d_in[2];
    const float* poses      = (const float*)d_in[3];
    const float* imu_drots  = (const float*)d_in[4];
    const float* imu_dtrans = (const float*)d_in[5];
    const float* imu_dvels  = (const float*)d_in[6];
    const float* dts        = (const float*)d_in[7];
    float* out = (float*)d_out;

    const int E = in_sizes[0] / 2;
    const int N = in_sizes[1] / 7;
    const int M = in_sizes[7];

    const size_t off_adjvel   = 6*(size_t)E;
    const size_t off_imurot   = off_adjvel + 3*(size_t)M;
    const size_t off_transvel = off_imurot + 3*(size_t)M;

    const int BLK = 256;
    const size_t need = 2 * (size_t)N * sizeof(float4);   // 32 B per node

    if (ws_size >= need) {
        float4* pn = (float4*)d_ws;
        pad_nodes_kernel<<<(N + BLK - 1) / BLK, BLK, 0, stream>>>(nodes, pn, N);
        const int half = (E + 1) / 2;
        edge_kernel2<<<(half + BLK - 1) / BLK, BLK, 0, stream>>>(
            (const int2*)edges, pn, poses, out, E, half);
        node_kernel<<<(M + BLK - 1) / BLK, BLK, 0, stream>>>(
            pn, vels, (const float4*)imu_drots, imu_dtrans, imu_dvels, dts, out, M,
            off_adjvel, off_imurot, off_transvel);
    } else {
        edge_kernel<<<(E + BLK - 1) / BLK, BLK, 0, stream>>>(edges, nodes, poses, out, E);
        node_kernel_raw<<<(M + BLK - 1) / BLK, BLK, 0, stream>>>(nodes, vels, imu_drots, imu_dtrans,
                                                                 imu_dvels, dts, out, M,
                                                                 off_adjvel, off_imurot, off_transvel);
    }
}